// Round 2
// baseline (2338.780 us; speedup 1.0000x reference)
//
#include <hip/hip_runtime.h>
#include <hip/hip_bf16.h>

#define T_ 64
#define B_ 128
#define S_ 512
#define E_ 256
#define H_ 512
#define TB_ (T_*B_)
#define H3_ (3*H_)

typedef __attribute__((ext_vector_type(8))) short short8;
typedef __attribute__((ext_vector_type(4))) short short4v;
typedef __attribute__((ext_vector_type(4))) float f32x4;
typedef __bf16 bf16x8 __attribute__((ext_vector_type(8)));

__device__ __forceinline__ short f2bf(float x){
    unsigned u = __builtin_bit_cast(unsigned, x);
    u += 0x7FFFu + ((u >> 16) & 1u);
    return (short)(u >> 16);
}
__device__ __forceinline__ float bf2f(short h){
    unsigned u = ((unsigned)(unsigned short)h) << 16;
    return __builtin_bit_cast(float, u);
}

__device__ __forceinline__ f32x4 mfma16(short8 a, short8 b, f32x4 c){
    return __builtin_amdgcn_mfma_f32_16x16x32_bf16(
        __builtin_bit_cast(bf16x8, a), __builtin_bit_cast(bf16x8, b), c, 0, 0, 0);
}

__device__ __forceinline__ f32x4 zero4(){ f32x4 z; z[0]=0.f; z[1]=0.f; z[2]=0.f; z[3]=0.f; return z; }

// load 8 consecutive fp32, produce hi/lo bf16 split fragments
__device__ __forceinline__ void load_cvt_frag(const float* __restrict__ p, short8& hi, short8& lo){
    const f32x4 v0 = *(const f32x4*)(p);
    const f32x4 v1 = *(const f32x4*)(p + 4);
    #pragma unroll
    for(int i=0;i<8;++i){
        float x = (i<4) ? v0[i] : v1[i-4];
        short h = f2bf(x);
        hi[i] = h;
        lo[i] = f2bf(x - bf2f(h));
    }
}
__device__ __forceinline__ short8 load_cvt8(const float* __restrict__ p){
    const f32x4 v0 = *(const f32x4*)(p);
    const f32x4 v1 = *(const f32x4*)(p + 4);
    short8 r;
    #pragma unroll
    for(int i=0;i<8;++i){ float x = (i<4)? v0[i] : v1[i-4]; r[i] = f2bf(x); }
    return r;
}

// ---------------- K0: weight prep (fp32 -> bf16 hi/lo splits) ----------------
__global__ __launch_bounds__(256) void k_prep(
    const float* __restrict__ w_hh, const float* __restrict__ w_ih,
    const float* __restrict__ w_in, const float* __restrict__ w_out,
    short* __restrict__ wh_hi, short* __restrict__ wh_lo,
    short* __restrict__ wi_hi, short* __restrict__ wi_lo,
    short* __restrict__ win_hi, short* __restrict__ win_lo,
    short* __restrict__ wout_bf)
{
    const int stride = gridDim.x * 256;
    const int i0 = blockIdx.x * 256 + threadIdx.x;
    for(int i = i0; i < H3_*H_; i += stride){
        float x = w_hh[i]; short h = f2bf(x); wh_hi[i] = h; wh_lo[i] = f2bf(x - bf2f(h));
    }
    for(int i = i0; i < H3_*E_; i += stride){
        float x = w_ih[i]; short h = f2bf(x); wi_hi[i] = h; wi_lo[i] = f2bf(x - bf2f(h));
    }
    for(int i = i0; i < H_*H_; i += stride){
        float x = w_in[i]; short h = f2bf(x); win_hi[i] = h; win_lo[i] = f2bf(x - bf2f(h));
    }
    for(int i = i0; i < H_*2*H_; i += stride){
        wout_bf[i] = f2bf(w_out[i]);
    }
}

// ---------------- K2: one GRU step (fused gx+gh GEMM + gates), split-3 -------
// grid (8 m-tiles of 16 b, 32 j-groups of 16), block 64 (1 wave)
__global__ __launch_bounds__(64) void k_step(
    const float* __restrict__ h_prev, const float* __restrict__ x_t,
    const short* __restrict__ wh_hi, const short* __restrict__ wh_lo,
    const short* __restrict__ wi_hi, const short* __restrict__ wi_lo,
    const float* __restrict__ b_ih, const float* __restrict__ b_hh,
    float* __restrict__ h_out)
{
    const int lane = threadIdx.x;
    const int m0 = blockIdx.x * 16;
    const int j0 = blockIdx.y * 16;
    const int rowA = m0 + (lane & 15);
    const int kb = (lane >> 4) * 8;
    const int nc = lane & 15;

    f32x4 accR = zero4(), accZ = zero4(), accNH = zero4(), accNX = zero4();

    // h-phase: K = 512
    for(int k0 = 0; k0 < H_; k0 += 32){
        short8 ahi, alo;
        load_cvt_frag(h_prev + rowA*H_ + k0 + kb, ahi, alo);
        #pragma unroll
        for(int g = 0; g < 3; ++g){
            const int wrow = g*H_ + j0 + nc;
            const short8 bh = *(const short8*)(wh_hi + wrow*H_ + k0 + kb);
            const short8 bl = *(const short8*)(wh_lo + wrow*H_ + k0 + kb);
            f32x4& acc = (g==0) ? accR : (g==1) ? accZ : accNH;
            acc = mfma16(ahi, bh, acc);
            acc = mfma16(alo, bh, acc);
            acc = mfma16(ahi, bl, acc);
        }
    }
    // x-phase: K = 256
    for(int k0 = 0; k0 < E_; k0 += 32){
        short8 ahi, alo;
        load_cvt_frag(x_t + rowA*E_ + k0 + kb, ahi, alo);
        #pragma unroll
        for(int g = 0; g < 3; ++g){
            const int wrow = g*H_ + j0 + nc;
            const short8 bh = *(const short8*)(wi_hi + wrow*E_ + k0 + kb);
            const short8 bl = *(const short8*)(wi_lo + wrow*E_ + k0 + kb);
            f32x4& acc = (g==0) ? accR : (g==1) ? accZ : accNX;
            acc = mfma16(ahi, bh, acc);
            acc = mfma16(alo, bh, acc);
            acc = mfma16(ahi, bl, acc);
        }
    }
    // gates epilogue
    const int j = j0 + nc;
    const float bihR = b_ih[j],      bhhR = b_hh[j];
    const float bihZ = b_ih[H_+j],   bhhZ = b_hh[H_+j];
    const float bihN = b_ih[2*H_+j], bhhN = b_hh[2*H_+j];
    const int rbase = m0 + ((lane >> 4) << 2);
    #pragma unroll
    for(int r = 0; r < 4; ++r){
        const int b = rbase + r;
        const float hp = h_prev[b*H_ + j];
        const float rr = 1.f/(1.f + expf(-(accR[r] + bihR + bhhR)));
        const float zz = 1.f/(1.f + expf(-(accZ[r] + bihZ + bhhZ)));
        const float nn = tanhf(accNX[r] + bihN + rr*(accNH[r] + bhhN));
        h_out[b*H_ + j] = (1.f - zz)*nn + zz*hp;
    }
}

// ---------------- K3: tmat = h_all @ w_in^T  (split-3, fp32 out) -------------
// grid (128 m-tiles of 64, 8 n-tiles of 64), block 256
__global__ __launch_bounds__(256) void k_tmat(
    const float* __restrict__ h_all,
    const short* __restrict__ win_hi, const short* __restrict__ win_lo,
    float* __restrict__ tmat)
{
    const int lane = threadIdx.x & 63;
    const int wv = threadIdx.x >> 6;
    const int m0 = blockIdx.x*64 + wv*16;
    const int n0 = blockIdx.y*64;
    const int rowA = m0 + (lane & 15);
    const int kb = (lane >> 4) * 8;
    const int nc = lane & 15;
    f32x4 acc[4] = {zero4(), zero4(), zero4(), zero4()};
    for(int k0 = 0; k0 < H_; k0 += 32){
        short8 ahi, alo;
        load_cvt_frag(h_all + (size_t)rowA*H_ + k0 + kb, ahi, alo);
        #pragma unroll
        for(int nj = 0; nj < 4; ++nj){
            const int n = n0 + nj*16 + nc;
            const short8 bh = *(const short8*)(win_hi + n*H_ + k0 + kb);
            const short8 bl = *(const short8*)(win_lo + n*H_ + k0 + kb);
            acc[nj] = mfma16(ahi, bh, acc[nj]);
            acc[nj] = mfma16(alo, bh, acc[nj]);
            acc[nj] = mfma16(ahi, bl, acc[nj]);
        }
    }
    const int rbase = m0 + ((lane >> 4) << 2);
    #pragma unroll
    for(int nj = 0; nj < 4; ++nj){
        const int n = n0 + nj*16 + nc;
        #pragma unroll
        for(int r = 0; r < 4; ++r) tmat[(size_t)(rbase + r)*H_ + n] = acc[nj][r];
    }
}

// ---------------- K4: scores[t,b,s] = tmat[t,b,:]·ctx[s,b,:]  (split-3) ------
// grid (8 s-tiles of 64, 128 b), block 256
__global__ __launch_bounds__(256) void k_scores(
    const float* __restrict__ tmat, const float* __restrict__ ctx,
    float* __restrict__ attn)
{
    const int b = blockIdx.y;
    const int lane = threadIdx.x & 63;
    const int wv = threadIdx.x >> 6;
    const int m0 = wv*16;             // T rows
    const int n0 = blockIdx.x*64;     // S cols
    const int kb = (lane >> 4) * 8;
    const int nc = lane & 15;
    const float* Ab = tmat + (size_t)b*H_;
    const float* Bb = ctx  + (size_t)b*H_;
    const int rowA = m0 + (lane & 15);
    f32x4 acc[4] = {zero4(), zero4(), zero4(), zero4()};
    for(int k0 = 0; k0 < H_; k0 += 32){
        short8 ahi, alo;
        load_cvt_frag(Ab + (size_t)rowA*(B_*H_) + k0 + kb, ahi, alo);
        #pragma unroll
        for(int nj = 0; nj < 4; ++nj){
            const int n = n0 + nj*16 + nc;
            short8 bh, bl;
            load_cvt_frag(Bb + (size_t)n*(B_*H_) + k0 + kb, bh, bl);
            acc[nj] = mfma16(ahi, bh, acc[nj]);
            acc[nj] = mfma16(alo, bh, acc[nj]);
            acc[nj] = mfma16(ahi, bl, acc[nj]);
        }
    }
    const int rbase = m0 + ((lane >> 4) << 2);
    #pragma unroll
    for(int nj = 0; nj < 4; ++nj){
        const int s = n0 + nj*16 + nc;
        #pragma unroll
        for(int r = 0; r < 4; ++r){
            const int t = rbase + r;
            attn[((size_t)t*B_ + b)*S_ + s] = acc[nj][r];
        }
    }
}

// ---------------- K5: row softmax over S, in-place on attn -------------------
__global__ __launch_bounds__(64) void k_softmax(float* __restrict__ attn){
    const int row = blockIdx.x;
    float* p = attn + (size_t)row*S_;
    const int lane = threadIdx.x;
    float v[8];
    float mx = -1e30f;
    #pragma unroll
    for(int i = 0; i < 8; ++i){ v[i] = p[lane + i*64]; mx = fmaxf(mx, v[i]); }
    #pragma unroll
    for(int o = 32; o; o >>= 1) mx = fmaxf(mx, __shfl_xor(mx, o));
    float sm = 0.f;
    #pragma unroll
    for(int i = 0; i < 8; ++i){ v[i] = expf(v[i] - mx); sm += v[i]; }
    #pragma unroll
    for(int o = 32; o; o >>= 1) sm += __shfl_xor(sm, o);
    const float inv = 1.f/sm;
    #pragma unroll
    for(int i = 0; i < 8; ++i) p[lane + i*64] = v[i]*inv;
}

// ---------------- K6: wc[t,b,h] = sum_s a[t,b,s]*ctx[s,b,h]  (plain bf16) ----
// NN gemm -> LDS-transposed B tile. grid (8 h-tiles of 64, 128 b), block 256
#define KP 40
__global__ __launch_bounds__(256) void k_wc(
    const float* __restrict__ attn, const float* __restrict__ ctx,
    float* __restrict__ wc)
{
    const int b = blockIdx.y;
    const int n0 = blockIdx.x*64;
    __shared__ alignas(16) short As[64*KP];
    __shared__ alignas(16) short Bs[64*KP];
    const int lane = threadIdx.x & 63;
    const int wv = threadIdx.x >> 6;
    const int m0 = wv*16;
    const int nc = lane & 15;
    const int kb = (lane >> 4) * 8;
    f32x4 acc[4] = {zero4(), zero4(), zero4(), zero4()};
    for(int k0 = 0; k0 < S_; k0 += 32){
        __syncthreads();
        // stage A: 64 t-rows x 32 s
        #pragma unroll
        for(int p = 0; p < 2; ++p){
            int f4 = threadIdx.x + p*256;
            int row = f4 >> 3, kq = f4 & 7;
            const float* src = attn + ((size_t)row*B_ + b)*S_ + k0 + kq*4;
            f32x4 vv = *(const f32x4*)src;
            short4v s4;
            #pragma unroll
            for(int q = 0; q < 4; ++q) s4[q] = f2bf(vv[q]);
            *(short4v*)(As + row*KP + kq*4) = s4;
        }
        // stage B transposed: 32 s-rows x 64 h  ->  Bs[h][s]
        #pragma unroll
        for(int p = 0; p < 2; ++p){
            int f4 = threadIdx.x + p*256;
            int s = f4 >> 4, hq = f4 & 15;
            const float* src = ctx + ((size_t)(k0 + s)*B_ + b)*H_ + n0 + hq*4;
            f32x4 vv = *(const f32x4*)src;
            #pragma unroll
            for(int q = 0; q < 4; ++q) Bs[(hq*4 + q)*KP + s] = f2bf(vv[q]);
        }
        __syncthreads();
        const short8 af = *(const short8*)(As + (m0 + (lane & 15))*KP + kb);
        #pragma unroll
        for(int nj = 0; nj < 4; ++nj){
            const short8 bf = *(const short8*)(Bs + (nj*16 + nc)*KP + kb);
            acc[nj] = mfma16(af, bf, acc[nj]);
        }
    }
    const int rbase = m0 + ((lane >> 4) << 2);
    #pragma unroll
    for(int nj = 0; nj < 4; ++nj){
        const int h = n0 + nj*16 + nc;
        #pragma unroll
        for(int r = 0; r < 4; ++r){
            const int t = rbase + r;
            wc[((size_t)t*B_ + b)*H_ + h] = acc[nj][r];
        }
    }
}

// ---------------- K7: out = tanh(concat(wc,h) @ w_out^T) (plain bf16) --------
// grid (128 m-tiles of 64, 8 n-tiles of 64), block 256
__global__ __launch_bounds__(256) void k_out(
    const float* __restrict__ wc, const float* __restrict__ h_all,
    const short* __restrict__ wout_bf, float* __restrict__ outp)
{
    const int lane = threadIdx.x & 63;
    const int wv = threadIdx.x >> 6;
    const int m0 = blockIdx.x*64 + wv*16;
    const int n0 = blockIdx.y*64;
    const int rowA = m0 + (lane & 15);
    const int kb = (lane >> 4) * 8;
    const int nc = lane & 15;
    f32x4 acc[4] = {zero4(), zero4(), zero4(), zero4()};
    for(int kt = 0; kt < 32; ++kt){
        const int k0 = kt*32;
        const float* src = (k0 < H_) ? (wc + (size_t)rowA*H_ + k0 + kb)
                                     : (h_all + (size_t)rowA*H_ + (k0 - H_) + kb);
        const short8 a = load_cvt8(src);
        #pragma unroll
        for(int nj = 0; nj < 4; ++nj){
            const int n = n0 + nj*16 + nc;
            const short8 bf = *(const short8*)(wout_bf + (size_t)n*(2*H_) + k0 + kb);
            acc[nj] = mfma16(a, bf, acc[nj]);
        }
    }
    const int rbase = m0 + ((lane >> 4) << 2);
    #pragma unroll
    for(int nj = 0; nj < 4; ++nj){
        const int n = n0 + nj*16 + nc;
        #pragma unroll
        for(int r = 0; r < 4; ++r) outp[(size_t)(rbase + r)*H_ + n] = tanhf(acc[nj][r]);
    }
}

// ---------------- K8: pgen at t = T-1, pure fp32 -----------------------------
__global__ __launch_bounds__(64) void k_pgen(
    const float* __restrict__ wc, const float* __restrict__ h_all,
    const float* __restrict__ input, const float* __restrict__ w_pgen,
    const float* __restrict__ b_pgen, float* __restrict__ pg_out)
{
    const int b = blockIdx.x;
    const int lane = threadIdx.x;
    const float* wcb = wc    + ((size_t)(T_-1)*B_ + b)*H_;
    const float* hb  = h_all + ((size_t)(T_-1)*B_ + b)*H_;
    const float* xb  = input + ((size_t)(T_-1)*B_ + b)*E_;
    float s = 0.f;
    for(int k = lane; k < H_; k += 64) s += wcb[k]*w_pgen[k];
    for(int k = lane; k < H_; k += 64) s += hb[k]*w_pgen[H_ + k];
    for(int k = lane; k < E_; k += 64) s += xb[k]*w_pgen[2*H_ + k];
    #pragma unroll
    for(int o = 32; o; o >>= 1) s += __shfl_xor(s, o);
    if(lane == 0) pg_out[b] = 1.f/(1.f + expf(-(s + b_pgen[0])));
}

extern "C" void kernel_launch(void* const* d_in, const int* in_sizes, int n_in,
                              void* d_out, int out_size, void* d_ws, size_t ws_size,
                              hipStream_t stream)
{
    const float* input  = (const float*)d_in[0];
    const float* hidden = (const float*)d_in[1];
    const float* ctx    = (const float*)d_in[2];
    const float* w_ih   = (const float*)d_in[3];
    const float* w_hh   = (const float*)d_in[4];
    const float* b_ih   = (const float*)d_in[5];
    const float* b_hh   = (const float*)d_in[6];
    const float* w_in   = (const float*)d_in[7];
    const float* w_out  = (const float*)d_in[8];
    const float* w_pgen = (const float*)d_in[9];
    const float* b_pgen = (const float*)d_in[10];

    float* outp = (float*)d_out;                       // (T,B,H)
    float* attn = outp + (size_t)T_*B_*H_;             // (T,B,S)
    float* pgo  = attn + (size_t)T_*B_*S_;             // (1,B,1)

    char* ws = (char*)d_ws;
    size_t off = 0;
    auto alloc = [&](size_t bytes) -> void* {
        void* p = ws + off; off += (bytes + 255) & ~(size_t)255; return p;
    };
    short* wh_hi   = (short*)alloc((size_t)H3_*H_*2);
    short* wh_lo   = (short*)alloc((size_t)H3_*H_*2);
    short* wi_hi   = (short*)alloc((size_t)H3_*E_*2);
    short* wi_lo   = (short*)alloc((size_t)H3_*E_*2);
    short* win_hi  = (short*)alloc((size_t)H_*H_*2);
    short* win_lo  = (short*)alloc((size_t)H_*H_*2);
    short* wout_bf = (short*)alloc((size_t)H_*2*H_*2);
    float* h_all   = (float*)alloc((size_t)TB_*H_*4);
    float* tmat    = (float*)alloc((size_t)TB_*H_*4);
    float* wcb     = (float*)alloc((size_t)TB_*H_*4);
    (void)ws_size; (void)in_sizes; (void)n_in; (void)out_size;

    k_prep<<<1024, 256, 0, stream>>>(w_hh, w_ih, w_in, w_out,
                                     wh_hi, wh_lo, wi_hi, wi_lo, win_hi, win_lo, wout_bf);

    for(int t = 0; t < T_; ++t){
        const float* hp = (t == 0) ? hidden : (h_all + (size_t)(t-1)*B_*H_);
        k_step<<<dim3(8, 32), 64, 0, stream>>>(
            hp, input + (size_t)t*B_*E_,
            wh_hi, wh_lo, wi_hi, wi_lo, b_ih, b_hh,
            h_all + (size_t)t*B_*H_);
    }

    k_tmat<<<dim3(128, 8), 256, 0, stream>>>(h_all, win_hi, win_lo, tmat);
    k_scores<<<dim3(8, 128), 256, 0, stream>>>(tmat, ctx, attn);
    k_softmax<<<8192, 64, 0, stream>>>(attn);
    k_wc<<<dim3(8, 128), 256, 0, stream>>>(attn, ctx, wcb);
    k_out<<<dim3(128, 8), 256, 0, stream>>>(wcb, h_all, wout_bf, outp);
    k_pgen<<<128, 64, 0, stream>>>(wcb, h_all, input, w_pgen, b_pgen, pgo);
}